// Round 17
// baseline (40.565 us; speedup 1.0000x reference)
//
#include <hip/hip_runtime.h>

// Deformable Conv1d, two-stage MFMA, merged-phase double-buffered pipeline,
// SINGLE kernel.
//   GEMM1 (per k): xs_k[c][t] = sum_tau x[c][t0+tau] * S_k[tau][t]  (banded S in LDS)
//   GEMM2:         out[o][t]  = sum_{ck} w[o][ck] * xs[ck][t],  ck = c*3+k (w-native)
// R17 = R16 (8-wave blocks, mf=1, merged GEMM2(i-1)||GEMM1(i), xs dbuf,
//   LDS_BARRIER) + w-conversion folded into the prologue. R14's fold failed at
//   mf=2 (96-VGPR afr + staging > 128 cap -> spill); at mf=1 afr=48 VGPR and
//   staging fits. Deletes wcvt2 dispatch + serializing graph edge (~10-15% of
//   dur). GEMM1-D uses the R14-proven stride-3 u16 scatter.
#define BB 16
#define CI 128
#define CO 128
#define LL 4096
#define LOUT 4094
#define CK 384            // GEMM2 K = 128*3, ck = c*3+k (w-native)
#define TT 32             // t per tile
#define NTPB 4            // tiles per block
#define STS 72            // S_k row stride (ushort), 144B rows (16B-aligned)
#define XSS 400           // xs row stride (ushort), 800B rows (16B-aligned)

// LDS-visibility barrier WITHOUT vmcnt(0) drain (keeps prefetches in flight)
#define LDS_BARRIER() do { \
    asm volatile("s_waitcnt lgkmcnt(0)" ::: "memory"); \
    __builtin_amdgcn_s_barrier(); \
} while (0)

typedef short short8 __attribute__((ext_vector_type(8)));
typedef float floatx4 __attribute__((ext_vector_type(4)));

__device__ __forceinline__ ushort f2bf(float f) {   // RNE f32 -> bf16
    union { float f; uint u; } v; v.f = f;
    uint r = v.u + 0x7FFFu + ((v.u >> 16) & 1u);
    return (ushort)(r >> 16);
}
__device__ __forceinline__ uint pk(ushort a, ushort b) {
    return (uint)a | ((uint)b << 16);
}
__device__ __forceinline__ short8 cvt8(floatx4 v0, floatx4 v1) {
    union { uint u[4]; short8 s; } r;
    r.u[0] = pk(f2bf(v0[0]), f2bf(v0[1]));
    r.u[1] = pk(f2bf(v0[2]), f2bf(v0[3]));
    r.u[2] = pk(f2bf(v1[0]), f2bf(v1[1]));
    r.u[3] = pk(f2bf(v1[2]), f2bf(v1[3]));
    return r.s;
}

__global__ __launch_bounds__(512, 4)
void dconv1d_one_kernel(const float* __restrict__ x,
                        const float* __restrict__ offs,
                        const float* __restrict__ mask,
                        const float* __restrict__ w,
                        const float* __restrict__ bias,
                        float* __restrict__ out) {
    __shared__ ushort St[3][TT][STS];     // 13.5 KB sampling matrices (single)
    __shared__ ushort xs[2][TT][XSS];     // 2 x 25 KB xs tiles (double buffer)

    const int tid  = threadIdx.x;
    const int lane = tid & 63;
    const int wv   = tid >> 6;            // 0..7; wave owns rows wv*16..wv*16+15
    const int bid  = blockIdx.x;
    // XCD-chunked swizzle over 512: XCD (bid&7) owns lb [k*64,(k+1)*64) -> 2 b's.
    const int lb   = (bid & 7) * 64 + (bid >> 3);
    const int b    = lb >> 5;
    const int t0b  = (lb & 31) * (TT * NTPB);   // 128-t stripe

    const int r15   = lane & 15;
    const int acol8 = (lane >> 4) << 3;
    const int row16 = wv * 16 + r15;            // c (GEMM1 A) and o (GEMM2 A)

    // ---- prologue: HBM loads first (x window chunks 0..2, offs/mask) ----
    const float* xrow = x + ((size_t)b * CI + row16) * LL;
    floatx4 c0[2], c1[2], xn[2];                // x chunks 0,1,2 raw f32
    {
        const int tb0 = t0b + acol8;
        const int tb1 = t0b + 32 + acol8;
        const int tb2 = t0b + 64 + acol8;
        c0[0] = *(const floatx4*)(xrow + tb0); c0[1] = *(const floatx4*)(xrow + tb0 + 4);
        c1[0] = *(const floatx4*)(xrow + tb1); c1[1] = *(const floatx4*)(xrow + tb1 + 4);
        xn[0] = *(const floatx4*)(xrow + tb2); xn[1] = *(const floatx4*)(xrow + tb2 + 4);
    }

    const int ct  = tid & 31;                   // coef unit t (tid<96)
    const int ck_ = (tid >> 5) < 3 ? (tid >> 5) : 0;
    float of0 = 0.f, mv0 = 0.f, ofc = 0.f, mvc = 0.f, ofn = 0.f, mvn = 0.f;
    if (tid < 96) {
        const int g0 = t0b + ct;                // tile0 always < LOUT
        of0 = offs[((size_t)b * LOUT + g0) * 3 + ck_];
        mv0 = mask[((size_t)b * 3 + ck_) * LOUT + g0];
        const int g1 = t0b + TT + ct;           // tile1
        if (g1 < LOUT) {
            ofc = offs[((size_t)b * LOUT + g1) * 3 + ck_];
            mvc = mask[((size_t)b * 3 + ck_) * LOUT + g1];
        }
        const int g2 = t0b + 2 * TT + ct;       // tile2
        if (g2 < LOUT) {
            ofn = offs[((size_t)b * LOUT + g2) * 3 + ck_];
            mvn = mask[((size_t)b * 3 + ck_) * LOUT + g2];
        }
    }

    float bv[4];                                // bias for wave's 16 o-rows
#pragma unroll
    for (int r = 0; r < 4; ++r)
        bv[r] = bias[wv * 16 + ((lane >> 4) << 2) + r];

    // ---- zero St once (band positions tile-invariant) ----
    {
        uint* stz = (uint*)&St[0][0][0];
        for (int i = tid; i < 3 * TT * STS / 2; i += 512) stz[i] = 0;
    }

    // ---- w -> afr in-prologue (w rows contiguous in ck=c*3+k; L2/L3-hot) ----
    short8 afr[12];                       // persistent GEMM2 A, 48 VGPR, static idx
#pragma unroll
    for (int ks = 0; ks < 12; ++ks) {
        const float* wp = w + (size_t)row16 * CK + ks * 32 + acol8;
        afr[ks] = cvt8(*(const floatx4*)wp, *(const floatx4*)(wp + 4));
    }

    short8 axf[2];                              // current x window (2 chunks)
    axf[0] = cvt8(c0[0], c0[1]);
    axf[1] = cvt8(c1[0], c1[1]);
    LDS_BARRIER();                              // St zero visible

    // coef macro: writes St band for tile at T0 with given (of, mv)
#define COEF_TILE(T0, OF, MV) do { \
    if (tid < 96) { \
        const int gt = (T0) + ct; \
        float cc0 = 0.f, cc1 = 0.f, cc2 = 0.f, cc3 = 0.f; \
        if (gt < LOUT) { \
            const float gtf = (float)gt; \
            float T = (gtf + (float)ck_) + (OF); \
            T = fminf(fmaxf(T, gtf), gtf + 2.0f); \
            int U = (int)floorf(T); \
            if (U > LL - 2) U = LL - 2; \
            const float Uf = (float)U; \
            const float G0 = fmaxf(0.f, 1.f - fabsf(Uf - T)) * (MV); \
            const float G1 = fmaxf(0.f, 1.f - fabsf(Uf + 1.f - T)) * (MV); \
            const int d0 = U - gt; \
            cc0 = (d0 == 0) ? G0 : 0.f; \
            cc1 = (d0 == 0) ? G1 : ((d0 == 1) ? G0 : 0.f); \
            cc2 = (d0 == 1) ? G1 : ((d0 == 2) ? G0 : 0.f); \
            cc3 = (d0 == 2) ? G1 : 0.f; \
        } \
        St[ck_][ct][ct + 0] = f2bf(cc0); \
        St[ck_][ct][ct + 1] = f2bf(cc1); \
        St[ck_][ct][ct + 2] = f2bf(cc2); \
        St[ck_][ct][ct + 3] = f2bf(cc3); \
    } \
} while (0)

    // GEMM1 tile I: x-window(axf) . S -> xs[I&1], D scattered to ck=c*3+k
#define GEMM1_TILE(I) do { \
    _Pragma("unroll") \
    for (int k = 0; k < 3; ++k) { \
        floatx4 a1[2]; \
        _Pragma("unroll") \
        for (int nf = 0; nf < 2; ++nf) { \
            floatx4 z = {0.f, 0.f, 0.f, 0.f}; \
            a1[nf] = z; \
        } \
        _Pragma("unroll") \
        for (int ks1 = 0; ks1 < 2; ++ks1) { \
            const short8 bfa = *(const short8*)(&St[k][r15][ks1 * 32 + acol8]); \
            const short8 bfb = *(const short8*)(&St[k][16 + r15][ks1 * 32 + acol8]); \
            a1[0] = __builtin_amdgcn_mfma_f32_16x16x32_bf16(axf[ks1], bfa, a1[0], 0, 0, 0); \
            a1[1] = __builtin_amdgcn_mfma_f32_16x16x32_bf16(axf[ks1], bfb, a1[1], 0, 0, 0); \
        } \
        _Pragma("unroll") \
        for (int nf = 0; nf < 2; ++nf) { \
            const int tcol = nf * 16 + r15; \
            const int cb   = wv * 16 + ((lane >> 4) << 2); \
            _Pragma("unroll") \
            for (int r = 0; r < 4; ++r) \
                xs[(I) & 1][tcol][(cb + r) * 3 + k] = f2bf(a1[nf][r]); \
        } \
    } \
} while (0)

    // GEMM2 tile J: afr . xs[J&1] -> out  (wave: 16 o-rows, mf=1)
#define GEMM2_TILE(J) do { \
    const int t0j = t0b + (J) * TT; \
    floatx4 acc[2]; \
    _Pragma("unroll") \
    for (int nf = 0; nf < 2; ++nf) { \
        floatx4 z = {0.f, 0.f, 0.f, 0.f}; \
        acc[nf] = z; \
    } \
    _Pragma("unroll") \
    for (int ks = 0; ks < 12; ++ks) { \
        const short8 bf0 = *(const short8*)(&xs[(J) & 1][r15][ks * 32 + acol8]); \
        const short8 bf1 = *(const short8*)(&xs[(J) & 1][16 + r15][ks * 32 + acol8]); \
        acc[0] = __builtin_amdgcn_mfma_f32_16x16x32_bf16(afr[ks], bf0, acc[0], 0, 0, 0); \
        acc[1] = __builtin_amdgcn_mfma_f32_16x16x32_bf16(afr[ks], bf1, acc[1], 0, 0, 0); \
    } \
    _Pragma("unroll") \
    for (int r = 0; r < 4; ++r) { \
        const int o = wv * 16 + ((lane >> 4) << 2) + r; \
        float* orow = out + ((size_t)b * CO + o) * LOUT; \
        _Pragma("unroll") \
        for (int nf = 0; nf < 2; ++nf) { \
            const int gt = t0j + nf * 16 + r15; \
            if (gt < LOUT) orow[gt] = acc[nf][r] + bv[r]; \
        } \
    } \
} while (0)

    // ---- prologue coef(0) ----
    COEF_TILE(t0b, of0, mv0);
    LDS_BARRIER();                              // St(0) ready

#pragma unroll 1
    for (int it = 0; it < NTPB; ++it) {
        // ======== interval A: GEMM2(it-1) || GEMM1(it) ========
        if (it > 0) GEMM2_TILE(it - 1);
        GEMM1_TILE(it);
        LDS_BARRIER();   // xs[it&1] ready; St free to overwrite

        // ======== interval B: coef(it+1) -> St; rotate; prefetch ========
        if (it + 1 < NTPB) {
            COEF_TILE(t0b + (it + 1) * TT, ofc, mvc);
            ofc = ofn; mvc = mvn;
            if (it + 3 < NTPB && tid < 96) {    // only tile3 left to load (it==0)
                const int g = t0b + (it + 3) * TT + ct;
                ofn = 0.f; mvn = 0.f;
                if (g < LOUT) {
                    ofn = offs[((size_t)b * LOUT + g) * 3 + ck_];
                    mvn = mask[((size_t)b * 3 + ck_) * LOUT + g];
                }
            }
            axf[0] = axf[1];                    // rotate x window
            axf[1] = cvt8(xn[0], xn[1]);
            if (it + 3 <= NTPB) {               // chunks 3,4
                int tb = t0b + (it + 3) * 32 + acol8;
                if (tb > LL - 8) tb = LL - 8;   // clamped lanes hit zero St rows
                xn[0] = *(const floatx4*)(xrow + tb);
                xn[1] = *(const floatx4*)(xrow + tb + 4);
            }
            LDS_BARRIER();   // St(it+1) ready
        }
    }

    // ---- peel: GEMM2 for last tile (xs write fenced by loop's last barrier) ----
    GEMM2_TILE(NTPB - 1);
}

extern "C" void kernel_launch(void* const* d_in, const int* in_sizes, int n_in,
                              void* d_out, int out_size, void* d_ws, size_t ws_size,
                              hipStream_t stream) {
    const float* x    = (const float*)d_in[0];
    const float* offs = (const float*)d_in[1];
    const float* mask = (const float*)d_in[2];
    const float* w    = (const float*)d_in[3];
    const float* bias = (const float*)d_in[4];
    float* out = (float*)d_out;

    dconv1d_one_kernel<<<dim3(512), dim3(512), 0, stream>>>(
        x, offs, mask, w, bias, out);
}

// Round 18
// 32.655 us; speedup vs baseline: 1.2422x; 1.2422x over previous
//
#include <hip/hip_runtime.h>

// Deformable Conv1d, two-stage MFMA + merged-phase double-buffered pipeline.
//   GEMM1 (per k): xs_k[c][t] = sum_tau x[c][t0+tau] * S_k[tau][t]  (banded S in LDS)
//   GEMM2:         out[o][t]  = sum_{ck'} w[o][ck'] * xs[ck'][t],  ck' = k*128+c
// R18 = R16 verbatim (best: 32.74 us). R17's w-fold spilled afr (3rd confirmed
//   spill from folding w-conversion; separate wcvt2 dispatch is cheaper).
//   Structure: 512-thr/8-wave blocks, mf=1, afr[12]=48 VGPR persistent,
//   16 waves/CU, merged GEMM2(i-1)||GEMM1(i) with xs double-buffer,
//   LDS_BARRIER (no vmcnt drain), XCD-chunked swizzle, 4-tile pipeline.
#define BB 16
#define CI 128
#define CO 128
#define LL 4096
#define LOUT 4094
#define CK 384            // GEMM2 K = 3*128, ck' = k*128+c
#define TT 32             // t per tile
#define NTPB 4            // tiles per block
#define STS 72            // S_k row stride (ushort), 144B rows (16B-aligned)
#define XSS 400           // xs row stride (ushort), 800B rows (16B-aligned)

// LDS-visibility barrier WITHOUT vmcnt(0) drain (keeps prefetches in flight)
#define LDS_BARRIER() do { \
    asm volatile("s_waitcnt lgkmcnt(0)" ::: "memory"); \
    __builtin_amdgcn_s_barrier(); \
} while (0)

typedef short short8 __attribute__((ext_vector_type(8)));
typedef float floatx4 __attribute__((ext_vector_type(4)));

__device__ __forceinline__ ushort f2bf(float f) {   // RNE f32 -> bf16
    union { float f; uint u; } v; v.f = f;
    uint r = v.u + 0x7FFFu + ((v.u >> 16) & 1u);
    return (ushort)(r >> 16);
}
__device__ __forceinline__ uint pk(ushort a, ushort b) {
    return (uint)a | ((uint)b << 16);
}
__device__ __forceinline__ short8 cvt8(floatx4 v0, floatx4 v1) {
    union { uint u[4]; short8 s; } r;
    r.u[0] = pk(f2bf(v0[0]), f2bf(v0[1]));
    r.u[1] = pk(f2bf(v0[2]), f2bf(v0[3]));
    r.u[2] = pk(f2bf(v1[0]), f2bf(v1[1]));
    r.u[3] = pk(f2bf(v1[2]), f2bf(v1[3]));
    return r.s;
}

// ---- w[o][c][k] f32 -> wbf2[o][k*128+c] bf16 ----
__global__ __launch_bounds__(256)
void wcvt2_kernel(const float* __restrict__ w, ushort* __restrict__ wbf2) {
    const int i = blockIdx.x * 256 + threadIdx.x;   // o*128 + c
    const int o = i >> 7, c = i & 127;
    const float w0 = w[i * 3 + 0], w1 = w[i * 3 + 1], w2 = w[i * 3 + 2];
    wbf2[o * CK +       c] = f2bf(w0);
    wbf2[o * CK + 128 + c] = f2bf(w1);
    wbf2[o * CK + 256 + c] = f2bf(w2);
}

__global__ __launch_bounds__(512, 4)
void dconv1d_merge_kernel(const float* __restrict__ x,
                          const float* __restrict__ offs,
                          const float* __restrict__ mask,
                          const ushort* __restrict__ wbf2,
                          const float* __restrict__ bias,
                          float* __restrict__ out) {
    __shared__ ushort St[3][TT][STS];     // 13.5 KB sampling matrices (single)
    __shared__ ushort xs[2][TT][XSS];     // 2 x 25 KB xs tiles (double buffer)

    const int tid  = threadIdx.x;
    const int lane = tid & 63;
    const int wv   = tid >> 6;            // 0..7; wave owns rows wv*16..wv*16+15
    const int bid  = blockIdx.x;
    // XCD-chunked swizzle over 512: XCD (bid&7) owns lb [k*64,(k+1)*64) -> 2 b's.
    const int lb   = (bid & 7) * 64 + (bid >> 3);
    const int b    = lb >> 5;
    const int t0b  = (lb & 31) * (TT * NTPB);   // 128-t stripe

    const int r15   = lane & 15;
    const int acol8 = (lane >> 4) << 3;
    const int row16 = wv * 16 + r15;            // c (GEMM1 A) and o (GEMM2 A)

    // ---- prologue: issue ALL early loads back-to-back ----
    short8 afr[12];                       // persistent GEMM2 A, 48 VGPR, static idx
#pragma unroll
    for (int ks = 0; ks < 12; ++ks)
        afr[ks] = *(const short8*)(wbf2 + (size_t)row16 * CK + ks * 32 + acol8);

    const float* xrow = x + ((size_t)b * CI + row16) * LL;
    floatx4 c0[2], c1[2], xn[2];                // x chunks 0,1,2 raw f32
    {
        const int tb0 = t0b + acol8;
        const int tb1 = t0b + 32 + acol8;
        const int tb2 = t0b + 64 + acol8;
        c0[0] = *(const floatx4*)(xrow + tb0); c0[1] = *(const floatx4*)(xrow + tb0 + 4);
        c1[0] = *(const floatx4*)(xrow + tb1); c1[1] = *(const floatx4*)(xrow + tb1 + 4);
        xn[0] = *(const floatx4*)(xrow + tb2); xn[1] = *(const floatx4*)(xrow + tb2 + 4);
    }

    const int ct  = tid & 31;                   // coef unit t (tid<96)
    const int ck_ = (tid >> 5) < 3 ? (tid >> 5) : 0;
    float of0 = 0.f, mv0 = 0.f, ofc = 0.f, mvc = 0.f, ofn = 0.f, mvn = 0.f;
    if (tid < 96) {
        const int g0 = t0b + ct;                // tile0 always < LOUT
        of0 = offs[((size_t)b * LOUT + g0) * 3 + ck_];
        mv0 = mask[((size_t)b * 3 + ck_) * LOUT + g0];
        const int g1 = t0b + TT + ct;           // tile1
        if (g1 < LOUT) {
            ofc = offs[((size_t)b * LOUT + g1) * 3 + ck_];
            mvc = mask[((size_t)b * 3 + ck_) * LOUT + g1];
        }
        const int g2 = t0b + 2 * TT + ct;       // tile2
        if (g2 < LOUT) {
            ofn = offs[((size_t)b * LOUT + g2) * 3 + ck_];
            mvn = mask[((size_t)b * 3 + ck_) * LOUT + g2];
        }
    }

    float bv[4];                                // bias for wave's 16 o-rows
#pragma unroll
    for (int r = 0; r < 4; ++r)
        bv[r] = bias[wv * 16 + ((lane >> 4) << 2) + r];

    // ---- zero St once (band positions tile-invariant) ----
    {
        uint* stz = (uint*)&St[0][0][0];
        for (int i = tid; i < 3 * TT * STS / 2; i += 512) stz[i] = 0;
    }

    short8 axf[2];                              // current x window (2 chunks)
    axf[0] = cvt8(c0[0], c0[1]);
    axf[1] = cvt8(c1[0], c1[1]);
    LDS_BARRIER();                              // St zero visible

    // coef macro: writes St band for tile at T0 with given (of, mv)
#define COEF_TILE(T0, OF, MV) do { \
    if (tid < 96) { \
        const int gt = (T0) + ct; \
        float cc0 = 0.f, cc1 = 0.f, cc2 = 0.f, cc3 = 0.f; \
        if (gt < LOUT) { \
            const float gtf = (float)gt; \
            float T = (gtf + (float)ck_) + (OF); \
            T = fminf(fmaxf(T, gtf), gtf + 2.0f); \
            int U = (int)floorf(T); \
            if (U > LL - 2) U = LL - 2; \
            const float Uf = (float)U; \
            const float G0 = fmaxf(0.f, 1.f - fabsf(Uf - T)) * (MV); \
            const float G1 = fmaxf(0.f, 1.f - fabsf(Uf + 1.f - T)) * (MV); \
            const int d0 = U - gt; \
            cc0 = (d0 == 0) ? G0 : 0.f; \
            cc1 = (d0 == 0) ? G1 : ((d0 == 1) ? G0 : 0.f); \
            cc2 = (d0 == 1) ? G1 : ((d0 == 2) ? G0 : 0.f); \
            cc3 = (d0 == 2) ? G1 : 0.f; \
        } \
        St[ck_][ct][ct + 0] = f2bf(cc0); \
        St[ck_][ct][ct + 1] = f2bf(cc1); \
        St[ck_][ct][ct + 2] = f2bf(cc2); \
        St[ck_][ct][ct + 3] = f2bf(cc3); \
    } \
} while (0)

    // GEMM1 tile I: x-window(axf) . S -> xs[I&1]  (wave: 16 c-rows, mf=1)
#define GEMM1_TILE(I) do { \
    _Pragma("unroll") \
    for (int k = 0; k < 3; ++k) { \
        floatx4 a1[2]; \
        _Pragma("unroll") \
        for (int nf = 0; nf < 2; ++nf) { \
            floatx4 z = {0.f, 0.f, 0.f, 0.f}; \
            a1[nf] = z; \
        } \
        _Pragma("unroll") \
        for (int ks1 = 0; ks1 < 2; ++ks1) { \
            const short8 bfa = *(const short8*)(&St[k][r15][ks1 * 32 + acol8]); \
            const short8 bfb = *(const short8*)(&St[k][16 + r15][ks1 * 32 + acol8]); \
            a1[0] = __builtin_amdgcn_mfma_f32_16x16x32_bf16(axf[ks1], bfa, a1[0], 0, 0, 0); \
            a1[1] = __builtin_amdgcn_mfma_f32_16x16x32_bf16(axf[ks1], bfb, a1[1], 0, 0, 0); \
        } \
        _Pragma("unroll") \
        for (int nf = 0; nf < 2; ++nf) { \
            const int tcol = nf * 16 + r15; \
            const int cb   = wv * 16 + ((lane >> 4) << 2); \
            uint2 q; \
            q.x = pk(f2bf(a1[nf][0]), f2bf(a1[nf][1])); \
            q.y = pk(f2bf(a1[nf][2]), f2bf(a1[nf][3])); \
            *(uint2*)(&xs[(I) & 1][tcol][k * 128 + cb]) = q; \
        } \
    } \
} while (0)

    // GEMM2 tile J: afr . xs[J&1] -> out  (wave: 16 o-rows, mf=1)
#define GEMM2_TILE(J) do { \
    const int t0j = t0b + (J) * TT; \
    floatx4 acc[2]; \
    _Pragma("unroll") \
    for (int nf = 0; nf < 2; ++nf) { \
        floatx4 z = {0.f, 0.f, 0.f, 0.f}; \
        acc[nf] = z; \
    } \
    _Pragma("unroll") \
    for (int ks = 0; ks < 12; ++ks) { \
        const short8 bf0 = *(const short8*)(&xs[(J) & 1][r15][ks * 32 + acol8]); \
        const short8 bf1 = *(const short8*)(&xs[(J) & 1][16 + r15][ks * 32 + acol8]); \
        acc[0] = __builtin_amdgcn_mfma_f32_16x16x32_bf16(afr[ks], bf0, acc[0], 0, 0, 0); \
        acc[1] = __builtin_amdgcn_mfma_f32_16x16x32_bf16(afr[ks], bf1, acc[1], 0, 0, 0); \
    } \
    _Pragma("unroll") \
    for (int r = 0; r < 4; ++r) { \
        const int o = wv * 16 + ((lane >> 4) << 2) + r; \
        float* orow = out + ((size_t)b * CO + o) * LOUT; \
        _Pragma("unroll") \
        for (int nf = 0; nf < 2; ++nf) { \
            const int gt = t0j + nf * 16 + r15; \
            if (gt < LOUT) orow[gt] = acc[nf][r] + bv[r]; \
        } \
    } \
} while (0)

    // ---- prologue coef(0) ----
    COEF_TILE(t0b, of0, mv0);
    LDS_BARRIER();                              // St(0) ready

#pragma unroll 1
    for (int it = 0; it < NTPB; ++it) {
        // ======== interval A: GEMM2(it-1) || GEMM1(it) ========
        if (it > 0) GEMM2_TILE(it - 1);
        GEMM1_TILE(it);
        LDS_BARRIER();   // xs[it&1] ready; St free to overwrite

        // ======== interval B: coef(it+1) -> St; rotate; prefetch ========
        if (it + 1 < NTPB) {
            COEF_TILE(t0b + (it + 1) * TT, ofc, mvc);
            ofc = ofn; mvc = mvn;
            if (it + 3 < NTPB && tid < 96) {    // only tile3 left to load (it==0)
                const int g = t0b + (it + 3) * TT + ct;
                ofn = 0.f; mvn = 0.f;
                if (g < LOUT) {
                    ofn = offs[((size_t)b * LOUT + g) * 3 + ck_];
                    mvn = mask[((size_t)b * 3 + ck_) * LOUT + g];
                }
            }
            axf[0] = axf[1];                    // rotate x window
            axf[1] = cvt8(xn[0], xn[1]);
            if (it + 3 <= NTPB) {               // chunks 3,4
                int tb = t0b + (it + 3) * 32 + acol8;
                if (tb > LL - 8) tb = LL - 8;   // clamped lanes hit zero St rows
                xn[0] = *(const floatx4*)(xrow + tb);
                xn[1] = *(const floatx4*)(xrow + tb + 4);
            }
            LDS_BARRIER();   // St(it+1) ready
        }
    }

    // ---- peel: GEMM2 for last tile (xs write fenced by loop's last barrier) ----
    GEMM2_TILE(NTPB - 1);
}

extern "C" void kernel_launch(void* const* d_in, const int* in_sizes, int n_in,
                              void* d_out, int out_size, void* d_ws, size_t ws_size,
                              hipStream_t stream) {
    const float* x    = (const float*)d_in[0];
    const float* offs = (const float*)d_in[1];
    const float* mask = (const float*)d_in[2];
    const float* w    = (const float*)d_in[3];
    const float* bias = (const float*)d_in[4];
    float* out = (float*)d_out;
    ushort* wbf2 = (ushort*)d_ws;            // 98.3 KB

    wcvt2_kernel<<<dim3(CO * CI / 256), dim3(256), 0, stream>>>(w, wbf2);
    dconv1d_merge_kernel<<<dim3(512), dim3(512), 0, stream>>>(
        x, offs, mask, wbf2, bias, out);
}